// Round 1
// 1822.719 us; speedup vs baseline: 1.5551x; 1.5551x over previous
//
#include <hip/hip_runtime.h>
#include <hip/hip_bf16.h>

typedef __bf16 bf16_t;
typedef bf16_t bf16x8 __attribute__((ext_vector_type(8)));
typedef float floatx4 __attribute__((ext_vector_type(4)));

#define BBS 2
#define SEQ 2048
#define DIM 1024
#define NH 16
#define HD 64
#define DFF_ 4096
#define NT (BBS*SEQ)

// ---------------------------------------------------------------------------
// Generic 64x64-tile batched GEMM: C = scale*(A @ B(^T)) + bias, optional relu.
// A: [M,K] row-major, f32 (AF32) or bf16. B: [K,N] (ldb), f32 (BF32) or bf16;
// or BT: [N,K] bf16 only. C: f32 or bf16. Staging converts f32->bf16 into LDS.
// mfma_f32_16x16x32_bf16; 4 waves, each 16 rows x 64 cols of the tile.
// ---------------------------------------------------------------------------
template<bool AF32, bool BF32, bool BT, bool OUTF32, bool RELU, bool BIAS>
__global__ __launch_bounds__(256) void gemm64(
    const void* __restrict__ Av, const void* __restrict__ Bv,
    const float* __restrict__ bias, void* __restrict__ Cout,
    int M, int N, int K, int lda, int ldb, int ldc,
    int batchH, long long sAb, long long sAh, long long sBb, long long sBh,
    long long sCb, long long sCh, float scale)
{
    int z = blockIdx.z;
    int zb = z / batchH, zh = z - zb * batchH;
    long long aoff = zb * sAb + zh * sAh;
    long long boff = zb * sBb + zh * sBh;
    long long coff = zb * sCb + zh * sCh;
    const bf16_t* A16 = (const bf16_t*)Av + aoff;
    const float*  A32 = (const float*)Av + aoff;
    const bf16_t* B16 = (const bf16_t*)Bv + boff;
    const float*  B32 = (const float*)Bv + boff;

    int tile_n = blockIdx.x * 64;
    int tile_m = blockIdx.y * 64;

    __shared__ __align__(16) bf16_t Alds[64 * 72];
    __shared__ __align__(16) bf16_t Blds[64 * 72];

    int tid  = threadIdx.x;
    int wave = tid >> 6;
    int lane = tid & 63;
    int lm = lane & 15;   // A row / B col / C col
    int lq = lane >> 4;   // quad

    floatx4 acc[4];
    #pragma unroll
    for (int i = 0; i < 4; ++i) acc[i] = (floatx4){0.f, 0.f, 0.f, 0.f};

    int s_row  = tid >> 2;          // 0..63
    int s_koff = (tid & 3) * 16;    // 0,16,32,48
    int nb_k   = tid >> 3;          // 0..31
    int nb_noff= (tid & 7) * 8;     // 0..56

    int nkt = K >> 6;
    for (int kt = 0; kt < nkt; ++kt) {
        int k0 = kt << 6;
        if constexpr (AF32) {       // A f32 [64r][64k] -> bf16 Alds[row*72+k]
            const float* src = A32 + (long long)(tile_m + s_row) * lda + (k0 + s_koff);
            float4 f0 = ((const float4*)src)[0];
            float4 f1 = ((const float4*)src)[1];
            float4 f2 = ((const float4*)src)[2];
            float4 f3 = ((const float4*)src)[3];
            bf16x8 h0, h1;
            h0[0]=(bf16_t)f0.x; h0[1]=(bf16_t)f0.y; h0[2]=(bf16_t)f0.z; h0[3]=(bf16_t)f0.w;
            h0[4]=(bf16_t)f1.x; h0[5]=(bf16_t)f1.y; h0[6]=(bf16_t)f1.z; h0[7]=(bf16_t)f1.w;
            h1[0]=(bf16_t)f2.x; h1[1]=(bf16_t)f2.y; h1[2]=(bf16_t)f2.z; h1[3]=(bf16_t)f2.w;
            h1[4]=(bf16_t)f3.x; h1[5]=(bf16_t)f3.y; h1[6]=(bf16_t)f3.z; h1[7]=(bf16_t)f3.w;
            *(bf16x8*)&Alds[s_row * 72 + s_koff]     = h0;
            *(bf16x8*)&Alds[s_row * 72 + s_koff + 8] = h1;
        } else {
            const bf16_t* src = A16 + (long long)(tile_m + s_row) * lda + (k0 + s_koff);
            *(uint4*)&Alds[s_row * 72 + s_koff]     = *(const uint4*)src;
            *(uint4*)&Alds[s_row * 72 + s_koff + 8] = *(const uint4*)(src + 8);
        }
        if constexpr (BT) {   // B bf16 [N,K]: direct copy -> Blds[n*72 + k]
            const bf16_t* src = B16 + (long long)(tile_n + s_row) * ldb + (k0 + s_koff);
            *(uint4*)&Blds[s_row * 72 + s_koff]     = *(const uint4*)src;
            *(uint4*)&Blds[s_row * 72 + s_koff + 8] = *(const uint4*)(src + 8);
        } else if constexpr (BF32) {  // B f32 [K,N]: transpose+convert
            #pragma unroll
            for (int kk = 0; kk < 64; kk += 32) {
                int k = kk + nb_k;
                const float* src = B32 + (long long)(k0 + k) * ldb + (tile_n + nb_noff);
                float4 f0 = ((const float4*)src)[0];
                float4 f1 = ((const float4*)src)[1];
                Blds[(nb_noff + 0) * 72 + k] = (bf16_t)f0.x;
                Blds[(nb_noff + 1) * 72 + k] = (bf16_t)f0.y;
                Blds[(nb_noff + 2) * 72 + k] = (bf16_t)f0.z;
                Blds[(nb_noff + 3) * 72 + k] = (bf16_t)f0.w;
                Blds[(nb_noff + 4) * 72 + k] = (bf16_t)f1.x;
                Blds[(nb_noff + 5) * 72 + k] = (bf16_t)f1.y;
                Blds[(nb_noff + 6) * 72 + k] = (bf16_t)f1.z;
                Blds[(nb_noff + 7) * 72 + k] = (bf16_t)f1.w;
            }
        } else {              // B bf16 [K,N]: transpose into n-major
            #pragma unroll
            for (int kk = 0; kk < 64; kk += 32) {
                int k = kk + nb_k;
                bf16x8 v = *(const bf16x8*)(B16 + (long long)(k0 + k) * ldb + (tile_n + nb_noff));
                #pragma unroll
                for (int j = 0; j < 8; ++j)
                    Blds[(nb_noff + j) * 72 + k] = v[j];
            }
        }
        __syncthreads();
        #pragma unroll
        for (int ks = 0; ks < 2; ++ks) {
            bf16x8 af = *(const bf16x8*)&Alds[(wave * 16 + lm) * 72 + ks * 32 + lq * 8];
            #pragma unroll
            for (int nt = 0; nt < 4; ++nt) {
                bf16x8 bfr = *(const bf16x8*)&Blds[(nt * 16 + lm) * 72 + ks * 32 + lq * 8];
                acc[nt] = __builtin_amdgcn_mfma_f32_16x16x32_bf16(af, bfr, acc[nt], 0, 0, 0);
            }
        }
        __syncthreads();
    }

    // epilogue: C/D layout col=lane&15, row=(lane>>4)*4+reg
    #pragma unroll
    for (int nt = 0; nt < 4; ++nt) {
        int col = tile_n + nt * 16 + lm;
        float bv = 0.f;
        if constexpr (BIAS) bv = bias[col];
        #pragma unroll
        for (int r = 0; r < 4; ++r) {
            int row = tile_m + wave * 16 + lq * 4 + r;
            float v = acc[nt][r] * scale + bv;
            if constexpr (RELU) v = fmaxf(v, 0.f);
            long long idx = coff + (long long)row * ldc + col;
            if constexpr (OUTF32) ((float*)Cout)[idx] = v;
            else                  ((bf16_t*)Cout)[idx] = (bf16_t)v;
        }
    }
}

// ---------------------------------------------------------------------------
// In-place row softmax over f32 [rows x 2048]; one wave per row.
// ---------------------------------------------------------------------------
__global__ __launch_bounds__(256) void softmax_f32(float* __restrict__ p)
{
    int row  = blockIdx.x * 4 + (threadIdx.x >> 6);
    int lane = threadIdx.x & 63;
    float* pr = p + (long long)row * SEQ;
    float v[32];
    float mx = -3.4e38f;
    #pragma unroll
    for (int it = 0; it < 8; ++it) {
        float4 c = *(const float4*)(pr + it * 256 + lane * 4);
        v[it*4+0] = c.x; v[it*4+1] = c.y; v[it*4+2] = c.z; v[it*4+3] = c.w;
        mx = fmaxf(mx, fmaxf(fmaxf(c.x, c.y), fmaxf(c.z, c.w)));
    }
    for (int off = 32; off; off >>= 1) mx = fmaxf(mx, __shfl_xor(mx, off));
    float s = 0.f;
    #pragma unroll
    for (int i = 0; i < 32; ++i) { v[i] = __expf(v[i] - mx); s += v[i]; }
    for (int off = 32; off; off >>= 1) s += __shfl_xor(s, off);
    float inv = 1.f / s;
    #pragma unroll
    for (int it = 0; it < 8; ++it) {
        float4 c;
        c.x = v[it*4+0]*inv; c.y = v[it*4+1]*inv; c.z = v[it*4+2]*inv; c.w = v[it*4+3]*inv;
        *(float4*)(pr + it * 256 + lane * 4) = c;
    }
}

// ---------------------------------------------------------------------------
// Sliding-window attention (|i-j| < 128), MFMA flash-style.
// One block (4 waves) = one 64-query tile of one (b,h). The +/-127 window of
// a 64-aligned query tile is covered by 5 aligned 64-key tiles; only the
// first and last are partially masked. Online softmax in the C-fragment
// layout (row = lq*4+r lives in a 16-lane group -> 16-lane shfl row-reduce).
// P goes through LDS to be re-shaped into the A-operand layout for PV.
// ---------------------------------------------------------------------------
__global__ __launch_bounds__(256) void sw_attn_mfma(
    const bf16_t* __restrict__ Q, const bf16_t* __restrict__ K,
    const bf16_t* __restrict__ V, bf16_t* __restrict__ ctx)
{
    int qt = blockIdx.x, h = blockIdx.y, b = blockIdx.z;
    int i0 = qt * 64;
    long long headoff = (long long)b * SEQ * DIM + (long long)h * HD;
    const bf16_t* Qb = Q + headoff;
    const bf16_t* Kb = K + headoff;
    const bf16_t* Vb = V + headoff;

    __shared__ __align__(16) bf16_t Klds[64 * 72];   // K tile [j][d]
    __shared__ __align__(16) bf16_t Vlds[64 * 72];   // V tile transposed [d][j]
    __shared__ __align__(16) bf16_t Plds[64 * 72];   // P tile [i][j] (per-wave rows)

    int tid  = threadIdx.x;
    int wave = tid >> 6;
    int lane = tid & 63;
    int lm = lane & 15;
    int lq = lane >> 4;
    int s_row  = tid >> 2;          // 0..63
    int s_koff = (tid & 3) * 16;    // 0,16,32,48
    int nb_j   = tid >> 3;          // 0..31
    int nb_doff= (tid & 7) * 8;     // 0..56

    // ---- stage Q tile once, pull per-wave A fragments into registers ----
    {
        const bf16_t* src = Qb + (long long)(i0 + s_row) * DIM + s_koff;
        *(uint4*)&Klds[s_row * 72 + s_koff]     = *(const uint4*)src;
        *(uint4*)&Klds[s_row * 72 + s_koff + 8] = *(const uint4*)(src + 8);
    }
    __syncthreads();
    bf16x8 qf0 = *(const bf16x8*)&Klds[(wave * 16 + lm) * 72 + 0 * 32 + lq * 8];
    bf16x8 qf1 = *(const bf16x8*)&Klds[(wave * 16 + lm) * 72 + 1 * 32 + lq * 8];
    __syncthreads();

    float m[4], l[4];
    floatx4 oacc[4];
    #pragma unroll
    for (int r = 0; r < 4; ++r) { m[r] = -1e30f; l[r] = 0.f; }
    #pragma unroll
    for (int nt = 0; nt < 4; ++nt) oacc[nt] = (floatx4){0.f, 0.f, 0.f, 0.f};

    int ibase = i0 + wave * 16 + lq * 4;   // row r lives at ibase + r

    for (int t = 0; t < 5; ++t) {
        int j0 = i0 - 128 + t * 64;        // 64-aligned: tile is all-in or all-out
        if (j0 < 0 || j0 >= SEQ) continue; // uniform per block
        // stage K [j][d] (direct) and V transposed [d][j]
        {
            const bf16_t* src = Kb + (long long)(j0 + s_row) * DIM + s_koff;
            *(uint4*)&Klds[s_row * 72 + s_koff]     = *(const uint4*)src;
            *(uint4*)&Klds[s_row * 72 + s_koff + 8] = *(const uint4*)(src + 8);
        }
        #pragma unroll
        for (int jj = 0; jj < 64; jj += 32) {
            int j = jj + nb_j;
            bf16x8 v = *(const bf16x8*)(Vb + (long long)(j0 + j) * DIM + nb_doff);
            #pragma unroll
            for (int e = 0; e < 8; ++e)
                Vlds[(nb_doff + e) * 72 + j] = v[e];
        }
        __syncthreads();

        // ---- scores: S = Q @ K^T (per wave: 16 rows x 64 cols) ----
        floatx4 sacc[4];
        #pragma unroll
        for (int nt = 0; nt < 4; ++nt) sacc[nt] = (floatx4){0.f, 0.f, 0.f, 0.f};
        #pragma unroll
        for (int ks = 0; ks < 2; ++ks) {
            bf16x8 af = ks ? qf1 : qf0;
            #pragma unroll
            for (int nt = 0; nt < 4; ++nt) {
                bf16x8 bfr = *(const bf16x8*)&Klds[(nt * 16 + lm) * 72 + ks * 32 + lq * 8];
                sacc[nt] = __builtin_amdgcn_mfma_f32_16x16x32_bf16(af, bfr, sacc[nt], 0, 0, 0);
            }
        }

        // ---- scale + band mask + online softmax ----
        float pmax[4] = {-3.4e38f, -3.4e38f, -3.4e38f, -3.4e38f};
        #pragma unroll
        for (int nt = 0; nt < 4; ++nt) {
            int j = j0 + nt * 16 + lm;
            #pragma unroll
            for (int r = 0; r < 4; ++r) {
                float s = sacc[nt][r] * 0.125f;
                int dd = ibase + r - j;
                if (dd > 127 || dd < -127) s = -3.0e38f;  // |i-j| < 128
                sacc[nt][r] = s;
                pmax[r] = fmaxf(pmax[r], s);
            }
        }
        #pragma unroll
        for (int off = 1; off < 16; off <<= 1) {
            #pragma unroll
            for (int r = 0; r < 4; ++r)
                pmax[r] = fmaxf(pmax[r], __shfl_xor(pmax[r], off));
        }
        float corr[4];
        #pragma unroll
        for (int r = 0; r < 4; ++r) {
            float mn = fmaxf(m[r], pmax[r]);   // m init -1e30 keeps this finite
            corr[r] = __expf(m[r] - mn);
            m[r] = mn;
            l[r] *= corr[r];
        }
        float rs[4] = {0.f, 0.f, 0.f, 0.f};
        #pragma unroll
        for (int nt = 0; nt < 4; ++nt) {
            #pragma unroll
            for (int r = 0; r < 4; ++r) {
                float p = __expf(sacc[nt][r] - m[r]);  // masked -> exp(-3e38) = 0
                sacc[nt][r] = p;
                rs[r] += p;
            }
        }
        #pragma unroll
        for (int off = 1; off < 16; off <<= 1) {
            #pragma unroll
            for (int r = 0; r < 4; ++r)
                rs[r] += __shfl_xor(rs[r], off);
        }
        #pragma unroll
        for (int r = 0; r < 4; ++r) l[r] += rs[r];

        // rescale O, spill P (bf16) to LDS in [i][j] so it rereads as A-frag
        #pragma unroll
        for (int nt = 0; nt < 4; ++nt) {
            #pragma unroll
            for (int r = 0; r < 4; ++r) {
                oacc[nt][r] *= corr[r];
                Plds[(wave * 16 + lq * 4 + r) * 72 + nt * 16 + lm] = (bf16_t)sacc[nt][r];
            }
        }
        // wave-internal write->read through same LDS array: compiler inserts
        // the lgkmcnt wait; LDS ops are in-order per wave. No barrier needed.

        // ---- PV: O += P @ V  (V pre-transposed to [d][j] = B-operand [col][k])
        #pragma unroll
        for (int ks = 0; ks < 2; ++ks) {
            bf16x8 af = *(const bf16x8*)&Plds[(wave * 16 + lm) * 72 + ks * 32 + lq * 8];
            #pragma unroll
            for (int nt = 0; nt < 4; ++nt) {
                bf16x8 bfr = *(const bf16x8*)&Vlds[(nt * 16 + lm) * 72 + ks * 32 + lq * 8];
                oacc[nt] = __builtin_amdgcn_mfma_f32_16x16x32_bf16(af, bfr, oacc[nt], 0, 0, 0);
            }
        }
        __syncthreads();   // protect Klds/Vlds before next tile's staging
    }

    // ---- epilogue: ctx[i][d] = O[i][d] / l[i] ----
    #pragma unroll
    for (int nt = 0; nt < 4; ++nt) {
        int d = nt * 16 + lm;
        #pragma unroll
        for (int r = 0; r < 4; ++r) {
            int i = ibase + r;
            ctx[(long long)(b * SEQ + i) * DIM + (long long)h * HD + d] =
                (bf16_t)(oacc[nt][r] / l[r]);
        }
    }
}

// ---------------------------------------------------------------------------
// full_out = LN(o1+x)*g1+be1 ; sw_out = LN(o2+x)*g2+be2 ; sum -> bf16 + f32
// One block per token. All f32 I/O except sum_bf.
// ---------------------------------------------------------------------------
__global__ __launch_bounds__(256) void add_ln2_kernel(
    const float* __restrict__ o1, const float* __restrict__ o2,
    const float* __restrict__ x,
    const float* __restrict__ g1, const float* __restrict__ be1,
    const float* __restrict__ g2, const float* __restrict__ be2,
    bf16_t* __restrict__ sum_bf, float* __restrict__ sum_f)
{
    __shared__ float red[8];
    int t = blockIdx.x, tid = threadIdx.x;
    long long base = (long long)t * DIM;
    float a[4], b[4];
    float s1 = 0.f, s2 = 0.f;
    #pragma unroll
    for (int k = 0; k < 4; ++k) {
        int c = tid + k * 256;
        float xv = x[base + c];
        a[k] = o1[base + c] + xv;
        b[k] = o2[base + c] + xv;
        s1 += a[k]; s2 += b[k];
    }
    for (int off = 32; off; off >>= 1) { s1 += __shfl_xor(s1, off); s2 += __shfl_xor(s2, off); }
    if ((tid & 63) == 0) { red[tid >> 6] = s1; red[(tid >> 6) + 4] = s2; }
    __syncthreads();
    float m1 = (red[0] + red[1] + red[2] + red[3]) * (1.f / DIM);
    float m2 = (red[4] + red[5] + red[6] + red[7]) * (1.f / DIM);
    __syncthreads();
    float v1 = 0.f, v2 = 0.f;
    #pragma unroll
    for (int k = 0; k < 4; ++k) {
        float d1 = a[k] - m1, d2 = b[k] - m2;
        v1 += d1 * d1; v2 += d2 * d2;
    }
    for (int off = 32; off; off >>= 1) { v1 += __shfl_xor(v1, off); v2 += __shfl_xor(v2, off); }
    if ((tid & 63) == 0) { red[tid >> 6] = v1; red[(tid >> 6) + 4] = v2; }
    __syncthreads();
    v1 = (red[0] + red[1] + red[2] + red[3]) * (1.f / DIM);
    v2 = (red[4] + red[5] + red[6] + red[7]) * (1.f / DIM);
    float i1 = rsqrtf(v1 + 1e-5f), i2 = rsqrtf(v2 + 1e-5f);
    #pragma unroll
    for (int k = 0; k < 4; ++k) {
        int c = tid + k * 256;
        float va = (a[k] - m1) * i1 * g1[c] + be1[c];
        float vb = (b[k] - m2) * i2 * g2[c] + be2[c];
        float s  = va + vb;
        sum_f[base + c]  = s;
        sum_bf[base + c] = (bf16_t)s;
    }
}

// enc = LN(ffn_out + sum)*g3+be3 -> f32 out
__global__ __launch_bounds__(256) void final_ln_kernel(
    const float* __restrict__ ffn, const float* __restrict__ res,
    const float* __restrict__ g, const float* __restrict__ be,
    float* __restrict__ out)
{
    __shared__ float red[4];
    int t = blockIdx.x, tid = threadIdx.x;
    long long base = (long long)t * DIM;
    float a[4]; float s = 0.f;
    #pragma unroll
    for (int k = 0; k < 4; ++k) {
        int c = tid + k * 256;
        a[k] = ffn[base + c] + res[base + c];
        s += a[k];
    }
    for (int off = 32; off; off >>= 1) s += __shfl_xor(s, off);
    if ((tid & 63) == 0) red[tid >> 6] = s;
    __syncthreads();
    float m = (red[0] + red[1] + red[2] + red[3]) * (1.f / DIM);
    __syncthreads();
    float v = 0.f;
    #pragma unroll
    for (int k = 0; k < 4; ++k) { float d = a[k] - m; v += d * d; }
    for (int off = 32; off; off >>= 1) v += __shfl_xor(v, off);
    if ((tid & 63) == 0) red[tid >> 6] = v;
    __syncthreads();
    v = (red[0] + red[1] + red[2] + red[3]) * (1.f / DIM);
    float inv = rsqrtf(v + 1e-5f);
    #pragma unroll
    for (int k = 0; k < 4; ++k) {
        int c = tid + k * 256;
        out[base + c] = (a[k] - m) * inv * g[c] + be[c];
    }
}

extern "C" void kernel_launch(void* const* d_in, const int* in_sizes, int n_in,
                              void* d_out, int out_size, void* d_ws, size_t ws_size,
                              hipStream_t stream)
{
    const float* x   = (const float*)d_in[0];
    const float* wq1 = (const float*)d_in[1];
    const float* bq1 = (const float*)d_in[2];
    const float* wk1 = (const float*)d_in[3];
    const float* bk1 = (const float*)d_in[4];
    const float* wv1 = (const float*)d_in[5];
    const float* bv1 = (const float*)d_in[6];
    const float* wo1 = (const float*)d_in[7];
    const float* bo1 = (const float*)d_in[8];
    const float* g1  = (const float*)d_in[9];
    const float* be1 = (const float*)d_in[10];
    const float* wq2 = (const float*)d_in[11];
    const float* bq2 = (const float*)d_in[12];
    const float* wk2 = (const float*)d_in[13];
    const float* bk2 = (const float*)d_in[14];
    const float* wv2 = (const float*)d_in[15];
    const float* bv2 = (const float*)d_in[16];
    const float* wo2 = (const float*)d_in[17];
    const float* bo2 = (const float*)d_in[18];
    const float* g2  = (const float*)d_in[19];
    const float* be2 = (const float*)d_in[20];
    const float* wc1 = (const float*)d_in[21];
    const float* bc1 = (const float*)d_in[22];
    const float* wc2 = (const float*)d_in[23];
    const float* bc2 = (const float*)d_in[24];
    const float* g3  = (const float*)d_in[25];
    const float* be3 = (const float*)d_in[26];

    float* enc_out  = (float*)d_out;
    float* attn_out = enc_out + (long long)NT * DIM;    // [B,H,S,S] f32

    // Workspace (88 MB peak, lifetime-aliased):
    const size_t NTD = (size_t)NT * DIM;                // 4194304
    bf16_t* qb = (bf16_t*)d_ws;            // 8MB  Q (bf16)
    bf16_t* kb = qb + NTD;                 // 8MB  K
    bf16_t* vb = kb + NTD;                 // 8MB  V
    bf16_t* cb = vb + NTD;                 // 8MB  ctx
    float*  o1 = (float*)(cb + NTD);       // 16MB o1 f32 -> later ffo
    float*  o2 = o1 + NTD;                 // 16MB o2 f32
    bf16_t* sumbf = (bf16_t*)(o2 + NTD);   // 8MB  sum bf16 (FFN input)
    float*  sumf  = (float*)(sumbf + NTD); // 16MB sum f32 (residual)
    bf16_t* hbuf = qb;                     // [NT,DFF] bf16 = 32MB (qb..cb dead)
    float*  ffo  = o1;                     // [NT,DIM] f32 (o1 dead after LN2)

    dim3 blk(256);
    const long long SD = (long long)SEQ * DIM;          // per-batch token stride
    const long long SS = (long long)SEQ * SEQ;

    // ---- sliding-window branch first (its QKV buffers are reused later) ----
    gemm64<true,true,false,false,false,true><<<dim3(16,64,1),blk,0,stream>>>(x, wq2, bq2, qb, NT,DIM,DIM, DIM,DIM,DIM, 1, 0,0,0,0,0,0, 1.f);
    gemm64<true,true,false,false,false,true><<<dim3(16,64,1),blk,0,stream>>>(x, wk2, bk2, kb, NT,DIM,DIM, DIM,DIM,DIM, 1, 0,0,0,0,0,0, 1.f);
    gemm64<true,true,false,false,false,true><<<dim3(16,64,1),blk,0,stream>>>(x, wv2, bv2, vb, NT,DIM,DIM, DIM,DIM,DIM, 1, 0,0,0,0,0,0, 1.f);
    sw_attn_mfma<<<dim3(SEQ/64, NH, BBS),blk,0,stream>>>(qb, kb, vb, cb);
    gemm64<false,true,false,true,false,true><<<dim3(16,64,1),blk,0,stream>>>(cb, wo2, bo2, o2, NT,DIM,DIM, DIM,DIM,DIM, 1, 0,0,0,0,0,0, 1.f);

    // ---- full-attention branch (reusing qb/kb/vb/cb) ----
    gemm64<true,true,false,false,false,true><<<dim3(16,64,1),blk,0,stream>>>(x, wq1, bq1, qb, NT,DIM,DIM, DIM,DIM,DIM, 1, 0,0,0,0,0,0, 1.f);
    gemm64<true,true,false,false,false,true><<<dim3(16,64,1),blk,0,stream>>>(x, wk1, bk1, kb, NT,DIM,DIM, DIM,DIM,DIM, 1, 0,0,0,0,0,0, 1.f);
    gemm64<true,true,false,false,false,true><<<dim3(16,64,1),blk,0,stream>>>(x, wv1, bv1, vb, NT,DIM,DIM, DIM,DIM,DIM, 1, 0,0,0,0,0,0, 1.f);

    // scores: per (b,h): Q_head @ K_head^T / 8 -> f32 attn region of d_out
    gemm64<false,false,true,true,false,false><<<dim3(32,32,32),blk,0,stream>>>(
        qb, kb, nullptr, attn_out, SEQ,SEQ,HD, DIM,DIM,SEQ,
        NH, SD,(long long)HD, SD,(long long)HD, (long long)NH*SS, SS, 0.125f);

    // softmax in place over 65536 rows of 2048 (f32)
    softmax_f32<<<dim3((BBS*NH*SEQ)/4),blk,0,stream>>>(attn_out);

    // ctx1 = probs(f32) @ V_head  (per (b,h): [2048,2048]@[2048,64]) -> cb
    gemm64<true,false,false,false,false,false><<<dim3(1,32,32),blk,0,stream>>>(
        attn_out, vb, nullptr, cb, SEQ,HD,SEQ, SEQ,DIM,DIM,
        NH, (long long)NH*SS, SS, SD,(long long)HD, SD,(long long)HD, 1.f);

    // out projection 1 -> o1 f32
    gemm64<false,true,false,true,false,true><<<dim3(16,64,1),blk,0,stream>>>(cb, wo1, bo1, o1, NT,DIM,DIM, DIM,DIM,DIM, 1, 0,0,0,0,0,0, 1.f);

    // sum = LN(o1+x) + LN(o2+x) -> sumbf + sumf
    add_ln2_kernel<<<dim3(NT),blk,0,stream>>>(o1, o2, x, g1, be1, g2, be2, sumbf, sumf);

    // FFN (hbuf aliases qb..cb; ffo aliases o1 — both dead by now)
    gemm64<false,true,false,false,true,true><<<dim3(64,64,1),blk,0,stream>>>(sumbf, wc1, bc1, hbuf, NT,DFF_,DIM, DIM,DFF_,DFF_, 1, 0,0,0,0,0,0, 1.f);
    gemm64<false,true,false,true,false,true><<<dim3(16,64,1),blk,0,stream>>>(hbuf, wc2, bc2, ffo, NT,DIM,DFF_, DFF_,DIM,DIM, 1, 0,0,0,0,0,0, 1.f);

    // enc = LN(ffn_out + sum)
    final_ln_kernel<<<dim3(NT),blk,0,stream>>>(ffo, sumf, g3, be3, enc_out);
}

// Round 2
// 1604.335 us; speedup vs baseline: 1.7668x; 1.1361x over previous
//
#include <hip/hip_runtime.h>
#include <hip/hip_bf16.h>

typedef __bf16 bf16_t;
typedef bf16_t bf16x8 __attribute__((ext_vector_type(8)));
typedef float floatx4 __attribute__((ext_vector_type(4)));

#define BBS 2
#define SEQ 2048
#define DIM 1024
#define NH 16
#define HD 64
#define DFF_ 4096
#define NT (BBS*SEQ)

// ---------------------------------------------------------------------------
// Generic 64x64-tile batched GEMM: C = scale*(A @ B(^T)) + bias, optional relu.
// A: [M,K] row-major, f32 (AF32) or bf16. B: [K,N] (ldb), f32 (BF32) or bf16;
// or BT: [N,K] bf16 only. C: f32 or bf16. Staging converts f32->bf16 into LDS.
// mfma_f32_16x16x32_bf16; 4 waves, each 16 rows x 64 cols of the tile.
// ---------------------------------------------------------------------------
template<bool AF32, bool BF32, bool BT, bool OUTF32, bool RELU, bool BIAS>
__global__ __launch_bounds__(256) void gemm64(
    const void* __restrict__ Av, const void* __restrict__ Bv,
    const float* __restrict__ bias, void* __restrict__ Cout,
    int M, int N, int K, int lda, int ldb, int ldc,
    int batchH, long long sAb, long long sAh, long long sBb, long long sBh,
    long long sCb, long long sCh, float scale)
{
    int z = blockIdx.z;
    int zb = z / batchH, zh = z - zb * batchH;
    long long aoff = zb * sAb + zh * sAh;
    long long boff = zb * sBb + zh * sBh;
    long long coff = zb * sCb + zh * sCh;
    const bf16_t* A16 = (const bf16_t*)Av + aoff;
    const float*  A32 = (const float*)Av + aoff;
    const bf16_t* B16 = (const bf16_t*)Bv + boff;
    const float*  B32 = (const float*)Bv + boff;

    int tile_n = blockIdx.x * 64;
    int tile_m = blockIdx.y * 64;

    __shared__ __align__(16) bf16_t Alds[64 * 72];
    __shared__ __align__(16) bf16_t Blds[64 * 72];

    int tid  = threadIdx.x;
    int wave = tid >> 6;
    int lane = tid & 63;
    int lm = lane & 15;   // A row / B col / C col
    int lq = lane >> 4;   // quad

    floatx4 acc[4];
    #pragma unroll
    for (int i = 0; i < 4; ++i) acc[i] = (floatx4){0.f, 0.f, 0.f, 0.f};

    int s_row  = tid >> 2;          // 0..63
    int s_koff = (tid & 3) * 16;    // 0,16,32,48
    int nb_k   = tid >> 3;          // 0..31
    int nb_noff= (tid & 7) * 8;     // 0..56

    int nkt = K >> 6;
    for (int kt = 0; kt < nkt; ++kt) {
        int k0 = kt << 6;
        if constexpr (AF32) {       // A f32 [64r][64k] -> bf16 Alds[row*72+k]
            const float* src = A32 + (long long)(tile_m + s_row) * lda + (k0 + s_koff);
            float4 f0 = ((const float4*)src)[0];
            float4 f1 = ((const float4*)src)[1];
            float4 f2 = ((const float4*)src)[2];
            float4 f3 = ((const float4*)src)[3];
            bf16x8 h0, h1;
            h0[0]=(bf16_t)f0.x; h0[1]=(bf16_t)f0.y; h0[2]=(bf16_t)f0.z; h0[3]=(bf16_t)f0.w;
            h0[4]=(bf16_t)f1.x; h0[5]=(bf16_t)f1.y; h0[6]=(bf16_t)f1.z; h0[7]=(bf16_t)f1.w;
            h1[0]=(bf16_t)f2.x; h1[1]=(bf16_t)f2.y; h1[2]=(bf16_t)f2.z; h1[3]=(bf16_t)f2.w;
            h1[4]=(bf16_t)f3.x; h1[5]=(bf16_t)f3.y; h1[6]=(bf16_t)f3.z; h1[7]=(bf16_t)f3.w;
            *(bf16x8*)&Alds[s_row * 72 + s_koff]     = h0;
            *(bf16x8*)&Alds[s_row * 72 + s_koff + 8] = h1;
        } else {
            const bf16_t* src = A16 + (long long)(tile_m + s_row) * lda + (k0 + s_koff);
            *(uint4*)&Alds[s_row * 72 + s_koff]     = *(const uint4*)src;
            *(uint4*)&Alds[s_row * 72 + s_koff + 8] = *(const uint4*)(src + 8);
        }
        if constexpr (BT) {   // B bf16 [N,K]: direct copy -> Blds[n*72 + k]
            const bf16_t* src = B16 + (long long)(tile_n + s_row) * ldb + (k0 + s_koff);
            *(uint4*)&Blds[s_row * 72 + s_koff]     = *(const uint4*)src;
            *(uint4*)&Blds[s_row * 72 + s_koff + 8] = *(const uint4*)(src + 8);
        } else if constexpr (BF32) {  // B f32 [K,N]: transpose+convert
            #pragma unroll
            for (int kk = 0; kk < 64; kk += 32) {
                int k = kk + nb_k;
                const float* src = B32 + (long long)(k0 + k) * ldb + (tile_n + nb_noff);
                float4 f0 = ((const float4*)src)[0];
                float4 f1 = ((const float4*)src)[1];
                Blds[(nb_noff + 0) * 72 + k] = (bf16_t)f0.x;
                Blds[(nb_noff + 1) * 72 + k] = (bf16_t)f0.y;
                Blds[(nb_noff + 2) * 72 + k] = (bf16_t)f0.z;
                Blds[(nb_noff + 3) * 72 + k] = (bf16_t)f0.w;
                Blds[(nb_noff + 4) * 72 + k] = (bf16_t)f1.x;
                Blds[(nb_noff + 5) * 72 + k] = (bf16_t)f1.y;
                Blds[(nb_noff + 6) * 72 + k] = (bf16_t)f1.z;
                Blds[(nb_noff + 7) * 72 + k] = (bf16_t)f1.w;
            }
        } else {              // B bf16 [K,N]: transpose into n-major
            #pragma unroll
            for (int kk = 0; kk < 64; kk += 32) {
                int k = kk + nb_k;
                bf16x8 v = *(const bf16x8*)(B16 + (long long)(k0 + k) * ldb + (tile_n + nb_noff));
                #pragma unroll
                for (int j = 0; j < 8; ++j)
                    Blds[(nb_noff + j) * 72 + k] = v[j];
            }
        }
        __syncthreads();
        #pragma unroll
        for (int ks = 0; ks < 2; ++ks) {
            bf16x8 af = *(const bf16x8*)&Alds[(wave * 16 + lm) * 72 + ks * 32 + lq * 8];
            #pragma unroll
            for (int nt = 0; nt < 4; ++nt) {
                bf16x8 bfr = *(const bf16x8*)&Blds[(nt * 16 + lm) * 72 + ks * 32 + lq * 8];
                acc[nt] = __builtin_amdgcn_mfma_f32_16x16x32_bf16(af, bfr, acc[nt], 0, 0, 0);
            }
        }
        __syncthreads();
    }

    // epilogue: C/D layout col=lane&15, row=(lane>>4)*4+reg
    #pragma unroll
    for (int nt = 0; nt < 4; ++nt) {
        int col = tile_n + nt * 16 + lm;
        float bv = 0.f;
        if constexpr (BIAS) bv = bias[col];
        #pragma unroll
        for (int r = 0; r < 4; ++r) {
            int row = tile_m + wave * 16 + lq * 4 + r;
            float v = acc[nt][r] * scale + bv;
            if constexpr (RELU) v = fmaxf(v, 0.f);
            long long idx = coff + (long long)row * ldc + col;
            if constexpr (OUTF32) ((float*)Cout)[idx] = v;
            else                  ((bf16_t*)Cout)[idx] = (bf16_t)v;
        }
    }
}

// ---------------------------------------------------------------------------
// Fused full attention: per block = one 64-query tile of one (b,h).
// Pass 1: stream all 32 K-tiles, track exact row max m and denom l online
//         (nothing stored). Pass 2: recompute QK^T (bitwise-identical MFMAs),
//         P = exp(s-m)/l, write normalized probs f32 to d_out ONCE, and
//         accumulate ctx += P @ V via MFMA. Saves ~1.5 GB of HBM round-trips
//         vs scores-GEMM + softmax + PV-GEMM (K/V are L2-resident per head).
// ---------------------------------------------------------------------------
__global__ __launch_bounds__(256) void full_attn_fused(
    const bf16_t* __restrict__ Q, const bf16_t* __restrict__ K,
    const bf16_t* __restrict__ V, float* __restrict__ probs,
    bf16_t* __restrict__ ctx)
{
    int qt = blockIdx.x, h = blockIdx.y, b = blockIdx.z;
    int i0 = qt * 64;
    long long headoff = (long long)b * SEQ * DIM + (long long)h * HD;
    const bf16_t* Qb = Q + headoff;
    const bf16_t* Kb = K + headoff;
    const bf16_t* Vb = V + headoff;
    float* Pb = probs + ((long long)(b * NH + h)) * SEQ * SEQ;

    __shared__ __align__(16) bf16_t Klds[64 * 72];   // K tile [j][d]  (pass1: even tile)
    __shared__ __align__(16) bf16_t Vlds[64 * 72];   // pass1: odd K tile; pass2: V^T [d][j]
    __shared__ __align__(16) bf16_t Plds[64 * 72];   // P tile [i][j]

    int tid  = threadIdx.x;
    int wave = tid >> 6;
    int lane = tid & 63;
    int lm = lane & 15;
    int lq = lane >> 4;
    int s_row  = tid >> 2;          // 0..63
    int s_koff = (tid & 3) * 16;    // 0,16,32,48
    int nb_j   = tid >> 3;          // 0..31
    int nb_doff= (tid & 7) * 8;     // 0..56

    // ---- stage Q tile once, pull per-wave A fragments into registers ----
    {
        const bf16_t* src = Qb + (long long)(i0 + s_row) * DIM + s_koff;
        *(uint4*)&Klds[s_row * 72 + s_koff]     = *(const uint4*)src;
        *(uint4*)&Klds[s_row * 72 + s_koff + 8] = *(const uint4*)(src + 8);
    }
    __syncthreads();
    bf16x8 qf0 = *(const bf16x8*)&Klds[(wave * 16 + lm) * 72 + 0 * 32 + lq * 8];
    bf16x8 qf1 = *(const bf16x8*)&Klds[(wave * 16 + lm) * 72 + 1 * 32 + lq * 8];
    __syncthreads();

    float m[4], l[4];
    #pragma unroll
    for (int r = 0; r < 4; ++r) { m[r] = -3.4e38f; l[r] = 0.f; }

    // ================= pass 1: exact row max + denom (128 keys/iter) ========
    for (int tt = 0; tt < SEQ / 128; ++tt) {
        int j0 = tt * 128;
        {   // stage two K tiles: j0..j0+63 -> Klds, j0+64..j0+127 -> Vlds
            const bf16_t* src = Kb + (long long)(j0 + s_row) * DIM + s_koff;
            *(uint4*)&Klds[s_row * 72 + s_koff]     = *(const uint4*)src;
            *(uint4*)&Klds[s_row * 72 + s_koff + 8] = *(const uint4*)(src + 8);
            const bf16_t* src2 = src + (long long)64 * DIM;
            *(uint4*)&Vlds[s_row * 72 + s_koff]     = *(const uint4*)src2;
            *(uint4*)&Vlds[s_row * 72 + s_koff + 8] = *(const uint4*)(src2 + 8);
        }
        __syncthreads();

        floatx4 s0[4], s1[4];
        #pragma unroll
        for (int nt = 0; nt < 4; ++nt) { s0[nt] = (floatx4){0,0,0,0}; s1[nt] = (floatx4){0,0,0,0}; }
        #pragma unroll
        for (int ks = 0; ks < 2; ++ks) {
            bf16x8 af = ks ? qf1 : qf0;
            #pragma unroll
            for (int nt = 0; nt < 4; ++nt) {
                bf16x8 b0 = *(const bf16x8*)&Klds[(nt * 16 + lm) * 72 + ks * 32 + lq * 8];
                s0[nt] = __builtin_amdgcn_mfma_f32_16x16x32_bf16(af, b0, s0[nt], 0, 0, 0);
                bf16x8 b1 = *(const bf16x8*)&Vlds[(nt * 16 + lm) * 72 + ks * 32 + lq * 8];
                s1[nt] = __builtin_amdgcn_mfma_f32_16x16x32_bf16(af, b1, s1[nt], 0, 0, 0);
            }
        }
        float pmax[4] = {-3.4e38f, -3.4e38f, -3.4e38f, -3.4e38f};
        #pragma unroll
        for (int nt = 0; nt < 4; ++nt) {
            #pragma unroll
            for (int r = 0; r < 4; ++r) {
                float a = s0[nt][r] * 0.125f, c = s1[nt][r] * 0.125f;
                s0[nt][r] = a; s1[nt][r] = c;
                pmax[r] = fmaxf(pmax[r], fmaxf(a, c));
            }
        }
        #pragma unroll
        for (int off = 1; off < 16; off <<= 1) {
            #pragma unroll
            for (int r = 0; r < 4; ++r)
                pmax[r] = fmaxf(pmax[r], __shfl_xor(pmax[r], off));
        }
        float rs[4] = {0.f, 0.f, 0.f, 0.f};
        #pragma unroll
        for (int r = 0; r < 4; ++r) {
            float mn = fmaxf(m[r], pmax[r]);
            l[r] *= __expf(m[r] - mn);
            m[r] = mn;
        }
        #pragma unroll
        for (int nt = 0; nt < 4; ++nt) {
            #pragma unroll
            for (int r = 0; r < 4; ++r)
                rs[r] += __expf(s0[nt][r] - m[r]) + __expf(s1[nt][r] - m[r]);
        }
        #pragma unroll
        for (int off = 1; off < 16; off <<= 1) {
            #pragma unroll
            for (int r = 0; r < 4; ++r)
                rs[r] += __shfl_xor(rs[r], off);
        }
        #pragma unroll
        for (int r = 0; r < 4; ++r) l[r] += rs[r];
        __syncthreads();
    }

    float invl[4];
    #pragma unroll
    for (int r = 0; r < 4; ++r) invl[r] = 1.f / l[r];

    floatx4 oacc[4];
    #pragma unroll
    for (int nt = 0; nt < 4; ++nt) oacc[nt] = (floatx4){0.f, 0.f, 0.f, 0.f};

    int irow = wave * 16 + lq * 4;   // tile-local row of acc reg r = irow + r

    // ================= pass 2: P = exp(s-m)/l -> probs + ctx ================
    for (int t = 0; t < SEQ / 64; ++t) {
        int j0 = t * 64;
        {   // K [j][d]
            const bf16_t* src = Kb + (long long)(j0 + s_row) * DIM + s_koff;
            *(uint4*)&Klds[s_row * 72 + s_koff]     = *(const uint4*)src;
            *(uint4*)&Klds[s_row * 72 + s_koff + 8] = *(const uint4*)(src + 8);
        }
        #pragma unroll
        for (int jj = 0; jj < 64; jj += 32) {   // V transposed [d][j]
            int j = jj + nb_j;
            bf16x8 v = *(const bf16x8*)(Vb + (long long)(j0 + j) * DIM + nb_doff);
            #pragma unroll
            for (int e = 0; e < 8; ++e)
                Vlds[(nb_doff + e) * 72 + j] = v[e];
        }
        __syncthreads();

        floatx4 sacc[4];
        #pragma unroll
        for (int nt = 0; nt < 4; ++nt) sacc[nt] = (floatx4){0,0,0,0};
        #pragma unroll
        for (int ks = 0; ks < 2; ++ks) {
            bf16x8 af = ks ? qf1 : qf0;
            #pragma unroll
            for (int nt = 0; nt < 4; ++nt) {
                bf16x8 bfr = *(const bf16x8*)&Klds[(nt * 16 + lm) * 72 + ks * 32 + lq * 8];
                sacc[nt] = __builtin_amdgcn_mfma_f32_16x16x32_bf16(af, bfr, sacc[nt], 0, 0, 0);
            }
        }
        // P, write probs, spill bf16 P to LDS for the PV A-fragment
        #pragma unroll
        for (int nt = 0; nt < 4; ++nt) {
            int col = j0 + nt * 16 + lm;
            #pragma unroll
            for (int r = 0; r < 4; ++r) {
                float p = __expf(sacc[nt][r] * 0.125f - m[r]) * invl[r];
                Pb[(long long)(i0 + irow + r) * SEQ + col] = p;
                Plds[(irow + r) * 72 + nt * 16 + lm] = (bf16_t)p;
            }
        }
        // wave-internal LDS write->read: in-order per wave, no barrier needed
        #pragma unroll
        for (int ks = 0; ks < 2; ++ks) {
            bf16x8 af = *(const bf16x8*)&Plds[(wave * 16 + lm) * 72 + ks * 32 + lq * 8];
            #pragma unroll
            for (int nt = 0; nt < 4; ++nt) {
                bf16x8 bfr = *(const bf16x8*)&Vlds[(nt * 16 + lm) * 72 + ks * 32 + lq * 8];
                oacc[nt] = __builtin_amdgcn_mfma_f32_16x16x32_bf16(af, bfr, oacc[nt], 0, 0, 0);
            }
        }
        __syncthreads();
    }

    // ---- epilogue: ctx[i][d] = O[i][d] (P was already normalized) ----
    #pragma unroll
    for (int nt = 0; nt < 4; ++nt) {
        int d = nt * 16 + lm;
        #pragma unroll
        for (int r = 0; r < 4; ++r) {
            int i = i0 + irow + r;
            ctx[(long long)(b * SEQ + i) * DIM + (long long)h * HD + d] = (bf16_t)oacc[nt][r];
        }
    }
}

// ---------------------------------------------------------------------------
// Sliding-window attention (|i-j| < 128), MFMA flash-style.
// One block (4 waves) = one 64-query tile of one (b,h).
// ---------------------------------------------------------------------------
__global__ __launch_bounds__(256) void sw_attn_mfma(
    const bf16_t* __restrict__ Q, const bf16_t* __restrict__ K,
    const bf16_t* __restrict__ V, bf16_t* __restrict__ ctx)
{
    int qt = blockIdx.x, h = blockIdx.y, b = blockIdx.z;
    int i0 = qt * 64;
    long long headoff = (long long)b * SEQ * DIM + (long long)h * HD;
    const bf16_t* Qb = Q + headoff;
    const bf16_t* Kb = K + headoff;
    const bf16_t* Vb = V + headoff;

    __shared__ __align__(16) bf16_t Klds[64 * 72];   // K tile [j][d]
    __shared__ __align__(16) bf16_t Vlds[64 * 72];   // V tile transposed [d][j]
    __shared__ __align__(16) bf16_t Plds[64 * 72];   // P tile [i][j] (per-wave rows)

    int tid  = threadIdx.x;
    int wave = tid >> 6;
    int lane = tid & 63;
    int lm = lane & 15;
    int lq = lane >> 4;
    int s_row  = tid >> 2;          // 0..63
    int s_koff = (tid & 3) * 16;    // 0,16,32,48
    int nb_j   = tid >> 3;          // 0..31
    int nb_doff= (tid & 7) * 8;     // 0..56

    // ---- stage Q tile once, pull per-wave A fragments into registers ----
    {
        const bf16_t* src = Qb + (long long)(i0 + s_row) * DIM + s_koff;
        *(uint4*)&Klds[s_row * 72 + s_koff]     = *(const uint4*)src;
        *(uint4*)&Klds[s_row * 72 + s_koff + 8] = *(const uint4*)(src + 8);
    }
    __syncthreads();
    bf16x8 qf0 = *(const bf16x8*)&Klds[(wave * 16 + lm) * 72 + 0 * 32 + lq * 8];
    bf16x8 qf1 = *(const bf16x8*)&Klds[(wave * 16 + lm) * 72 + 1 * 32 + lq * 8];
    __syncthreads();

    float m[4], l[4];
    floatx4 oacc[4];
    #pragma unroll
    for (int r = 0; r < 4; ++r) { m[r] = -1e30f; l[r] = 0.f; }
    #pragma unroll
    for (int nt = 0; nt < 4; ++nt) oacc[nt] = (floatx4){0.f, 0.f, 0.f, 0.f};

    int ibase = i0 + wave * 16 + lq * 4;   // row r lives at ibase + r

    for (int t = 0; t < 5; ++t) {
        int j0 = i0 - 128 + t * 64;        // 64-aligned: tile is all-in or all-out
        if (j0 < 0 || j0 >= SEQ) continue; // uniform per block
        // stage K [j][d] (direct) and V transposed [d][j]
        {
            const bf16_t* src = Kb + (long long)(j0 + s_row) * DIM + s_koff;
            *(uint4*)&Klds[s_row * 72 + s_koff]     = *(const uint4*)src;
            *(uint4*)&Klds[s_row * 72 + s_koff + 8] = *(const uint4*)(src + 8);
        }
        #pragma unroll
        for (int jj = 0; jj < 64; jj += 32) {
            int j = jj + nb_j;
            bf16x8 v = *(const bf16x8*)(Vb + (long long)(j0 + j) * DIM + nb_doff);
            #pragma unroll
            for (int e = 0; e < 8; ++e)
                Vlds[(nb_doff + e) * 72 + j] = v[e];
        }
        __syncthreads();

        // ---- scores: S = Q @ K^T (per wave: 16 rows x 64 cols) ----
        floatx4 sacc[4];
        #pragma unroll
        for (int nt = 0; nt < 4; ++nt) sacc[nt] = (floatx4){0.f, 0.f, 0.f, 0.f};
        #pragma unroll
        for (int ks = 0; ks < 2; ++ks) {
            bf16x8 af = ks ? qf1 : qf0;
            #pragma unroll
            for (int nt = 0; nt < 4; ++nt) {
                bf16x8 bfr = *(const bf16x8*)&Klds[(nt * 16 + lm) * 72 + ks * 32 + lq * 8];
                sacc[nt] = __builtin_amdgcn_mfma_f32_16x16x32_bf16(af, bfr, sacc[nt], 0, 0, 0);
            }
        }

        // ---- scale + band mask + online softmax ----
        float pmax[4] = {-3.4e38f, -3.4e38f, -3.4e38f, -3.4e38f};
        #pragma unroll
        for (int nt = 0; nt < 4; ++nt) {
            int j = j0 + nt * 16 + lm;
            #pragma unroll
            for (int r = 0; r < 4; ++r) {
                float s = sacc[nt][r] * 0.125f;
                int dd = ibase + r - j;
                if (dd > 127 || dd < -127) s = -3.0e38f;  // |i-j| < 128
                sacc[nt][r] = s;
                pmax[r] = fmaxf(pmax[r], s);
            }
        }
        #pragma unroll
        for (int off = 1; off < 16; off <<= 1) {
            #pragma unroll
            for (int r = 0; r < 4; ++r)
                pmax[r] = fmaxf(pmax[r], __shfl_xor(pmax[r], off));
        }
        float corr[4];
        #pragma unroll
        for (int r = 0; r < 4; ++r) {
            float mn = fmaxf(m[r], pmax[r]);   // m init -1e30 keeps this finite
            corr[r] = __expf(m[r] - mn);
            m[r] = mn;
            l[r] *= corr[r];
        }
        float rs[4] = {0.f, 0.f, 0.f, 0.f};
        #pragma unroll
        for (int nt = 0; nt < 4; ++nt) {
            #pragma unroll
            for (int r = 0; r < 4; ++r) {
                float p = __expf(sacc[nt][r] - m[r]);  // masked -> exp(-3e38) = 0
                sacc[nt][r] = p;
                rs[r] += p;
            }
        }
        #pragma unroll
        for (int off = 1; off < 16; off <<= 1) {
            #pragma unroll
            for (int r = 0; r < 4; ++r)
                rs[r] += __shfl_xor(rs[r], off);
        }
        #pragma unroll
        for (int r = 0; r < 4; ++r) l[r] += rs[r];

        // rescale O, spill P (bf16) to LDS in [i][j] so it rereads as A-frag
        #pragma unroll
        for (int nt = 0; nt < 4; ++nt) {
            #pragma unroll
            for (int r = 0; r < 4; ++r) {
                oacc[nt][r] *= corr[r];
                Plds[(wave * 16 + lq * 4 + r) * 72 + nt * 16 + lm] = (bf16_t)sacc[nt][r];
            }
        }
        // wave-internal write->read through same LDS array: compiler inserts
        // the lgkmcnt wait; LDS ops are in-order per wave. No barrier needed.

        // ---- PV: O += P @ V  (V pre-transposed to [d][j] = B-operand [col][k])
        #pragma unroll
        for (int ks = 0; ks < 2; ++ks) {
            bf16x8 af = *(const bf16x8*)&Plds[(wave * 16 + lm) * 72 + ks * 32 + lq * 8];
            #pragma unroll
            for (int nt = 0; nt < 4; ++nt) {
                bf16x8 bfr = *(const bf16x8*)&Vlds[(nt * 16 + lm) * 72 + ks * 32 + lq * 8];
                oacc[nt] = __builtin_amdgcn_mfma_f32_16x16x32_bf16(af, bfr, oacc[nt], 0, 0, 0);
            }
        }
        __syncthreads();   // protect Klds/Vlds before next tile's staging
    }

    // ---- epilogue: ctx[i][d] = O[i][d] / l[i] ----
    #pragma unroll
    for (int nt = 0; nt < 4; ++nt) {
        int d = nt * 16 + lm;
        #pragma unroll
        for (int r = 0; r < 4; ++r) {
            int i = ibase + r;
            ctx[(long long)(b * SEQ + i) * DIM + (long long)h * HD + d] =
                (bf16_t)(oacc[nt][r] / l[r]);
        }
    }
}

// ---------------------------------------------------------------------------
// full_out = LN(o1+x)*g1+be1 ; sw_out = LN(o2+x)*g2+be2 ; sum -> bf16 + f32
// One block per token. All f32 I/O except sum_bf.
// ---------------------------------------------------------------------------
__global__ __launch_bounds__(256) void add_ln2_kernel(
    const float* __restrict__ o1, const float* __restrict__ o2,
    const float* __restrict__ x,
    const float* __restrict__ g1, const float* __restrict__ be1,
    const float* __restrict__ g2, const float* __restrict__ be2,
    bf16_t* __restrict__ sum_bf, float* __restrict__ sum_f)
{
    __shared__ float red[8];
    int t = blockIdx.x, tid = threadIdx.x;
    long long base = (long long)t * DIM;
    float a[4], b[4];
    float s1 = 0.f, s2 = 0.f;
    #pragma unroll
    for (int k = 0; k < 4; ++k) {
        int c = tid + k * 256;
        float xv = x[base + c];
        a[k] = o1[base + c] + xv;
        b[k] = o2[base + c] + xv;
        s1 += a[k]; s2 += b[k];
    }
    for (int off = 32; off; off >>= 1) { s1 += __shfl_xor(s1, off); s2 += __shfl_xor(s2, off); }
    if ((tid & 63) == 0) { red[tid >> 6] = s1; red[(tid >> 6) + 4] = s2; }
    __syncthreads();
    float m1 = (red[0] + red[1] + red[2] + red[3]) * (1.f / DIM);
    float m2 = (red[4] + red[5] + red[6] + red[7]) * (1.f / DIM);
    __syncthreads();
    float v1 = 0.f, v2 = 0.f;
    #pragma unroll
    for (int k = 0; k < 4; ++k) {
        float d1 = a[k] - m1, d2 = b[k] - m2;
        v1 += d1 * d1; v2 += d2 * d2;
    }
    for (int off = 32; off; off >>= 1) { v1 += __shfl_xor(v1, off); v2 += __shfl_xor(v2, off); }
    if ((tid & 63) == 0) { red[tid >> 6] = v1; red[(tid >> 6) + 4] = v2; }
    __syncthreads();
    v1 = (red[0] + red[1] + red[2] + red[3]) * (1.f / DIM);
    v2 = (red[4] + red[5] + red[6] + red[7]) * (1.f / DIM);
    float i1 = rsqrtf(v1 + 1e-5f), i2 = rsqrtf(v2 + 1e-5f);
    #pragma unroll
    for (int k = 0; k < 4; ++k) {
        int c = tid + k * 256;
        float va = (a[k] - m1) * i1 * g1[c] + be1[c];
        float vb = (b[k] - m2) * i2 * g2[c] + be2[c];
        float s  = va + vb;
        sum_f[base + c]  = s;
        sum_bf[base + c] = (bf16_t)s;
    }
}

// enc = LN(ffn_out + sum)*g3+be3 -> f32 out
__global__ __launch_bounds__(256) void final_ln_kernel(
    const float* __restrict__ ffn, const float* __restrict__ res,
    const float* __restrict__ g, const float* __restrict__ be,
    float* __restrict__ out)
{
    __shared__ float red[4];
    int t = blockIdx.x, tid = threadIdx.x;
    long long base = (long long)t * DIM;
    float a[4]; float s = 0.f;
    #pragma unroll
    for (int k = 0; k < 4; ++k) {
        int c = tid + k * 256;
        a[k] = ffn[base + c] + res[base + c];
        s += a[k];
    }
    for (int off = 32; off; off >>= 1) s += __shfl_xor(s, off);
    if ((tid & 63) == 0) red[tid >> 6] = s;
    __syncthreads();
    float m = (red[0] + red[1] + red[2] + red[3]) * (1.f / DIM);
    __syncthreads();
    float v = 0.f;
    #pragma unroll
    for (int k = 0; k < 4; ++k) { float d = a[k] - m; v += d * d; }
    for (int off = 32; off; off >>= 1) v += __shfl_xor(v, off);
    if ((tid & 63) == 0) red[tid >> 6] = v;
    __syncthreads();
    v = (red[0] + red[1] + red[2] + red[3]) * (1.f / DIM);
    float inv = rsqrtf(v + 1e-5f);
    #pragma unroll
    for (int k = 0; k < 4; ++k) {
        int c = tid + k * 256;
        out[base + c] = (a[k] - m) * inv * g[c] + be[c];
    }
}

extern "C" void kernel_launch(void* const* d_in, const int* in_sizes, int n_in,
                              void* d_out, int out_size, void* d_ws, size_t ws_size,
                              hipStream_t stream)
{
    const float* x   = (const float*)d_in[0];
    const float* wq1 = (const float*)d_in[1];
    const float* bq1 = (const float*)d_in[2];
    const float* wk1 = (const float*)d_in[3];
    const float* bk1 = (const float*)d_in[4];
    const float* wv1 = (const float*)d_in[5];
    const float* bv1 = (const float*)d_in[6];
    const float* wo1 = (const float*)d_in[7];
    const float* bo1 = (const float*)d_in[8];
    const float* g1  = (const float*)d_in[9];
    const float* be1 = (const float*)d_in[10];
    const float* wq2 = (const float*)d_in[11];
    const float* bq2 = (const float*)d_in[12];
    const float* wk2 = (const float*)d_in[13];
    const float* bk2 = (const float*)d_in[14];
    const float* wv2 = (const float*)d_in[15];
    const float* bv2 = (const float*)d_in[16];
    const float* wo2 = (const float*)d_in[17];
    const float* bo2 = (const float*)d_in[18];
    const float* g2  = (const float*)d_in[19];
    const float* be2 = (const float*)d_in[20];
    const float* wc1 = (const float*)d_in[21];
    const float* bc1 = (const float*)d_in[22];
    const float* wc2 = (const float*)d_in[23];
    const float* bc2 = (const float*)d_in[24];
    const float* g3  = (const float*)d_in[25];
    const float* be3 = (const float*)d_in[26];

    float* enc_out  = (float*)d_out;
    float* attn_out = enc_out + (long long)NT * DIM;    // [B,H,S,S] f32

    // Workspace (88 MB peak, lifetime-aliased):
    const size_t NTD = (size_t)NT * DIM;                // 4194304
    bf16_t* qb = (bf16_t*)d_ws;            // 8MB  Q (bf16)
    bf16_t* kb = qb + NTD;                 // 8MB  K
    bf16_t* vb = kb + NTD;                 // 8MB  V
    bf16_t* cb = vb + NTD;                 // 8MB  ctx
    float*  o1 = (float*)(cb + NTD);       // 16MB o1 f32 -> later ffo
    float*  o2 = o1 + NTD;                 // 16MB o2 f32
    bf16_t* sumbf = (bf16_t*)(o2 + NTD);   // 8MB  sum bf16 (FFN input)
    float*  sumf  = (float*)(sumbf + NTD); // 16MB sum f32 (residual)
    bf16_t* hbuf = qb;                     // [NT,DFF] bf16 = 32MB (qb..cb dead)
    float*  ffo  = o1;                     // [NT,DIM] f32 (o1 dead after LN2)

    dim3 blk(256);

    // ---- sliding-window branch first (its QKV buffers are reused later) ----
    gemm64<true,true,false,false,false,true><<<dim3(16,64,1),blk,0,stream>>>(x, wq2, bq2, qb, NT,DIM,DIM, DIM,DIM,DIM, 1, 0,0,0,0,0,0, 1.f);
    gemm64<true,true,false,false,false,true><<<dim3(16,64,1),blk,0,stream>>>(x, wk2, bk2, kb, NT,DIM,DIM, DIM,DIM,DIM, 1, 0,0,0,0,0,0, 1.f);
    gemm64<true,true,false,false,false,true><<<dim3(16,64,1),blk,0,stream>>>(x, wv2, bv2, vb, NT,DIM,DIM, DIM,DIM,DIM, 1, 0,0,0,0,0,0, 1.f);
    sw_attn_mfma<<<dim3(SEQ/64, NH, BBS),blk,0,stream>>>(qb, kb, vb, cb);
    gemm64<false,true,false,true,false,true><<<dim3(16,64,1),blk,0,stream>>>(cb, wo2, bo2, o2, NT,DIM,DIM, DIM,DIM,DIM, 1, 0,0,0,0,0,0, 1.f);

    // ---- full-attention branch (reusing qb/kb/vb/cb) ----
    gemm64<true,true,false,false,false,true><<<dim3(16,64,1),blk,0,stream>>>(x, wq1, bq1, qb, NT,DIM,DIM, DIM,DIM,DIM, 1, 0,0,0,0,0,0, 1.f);
    gemm64<true,true,false,false,false,true><<<dim3(16,64,1),blk,0,stream>>>(x, wk1, bk1, kb, NT,DIM,DIM, DIM,DIM,DIM, 1, 0,0,0,0,0,0, 1.f);
    gemm64<true,true,false,false,false,true><<<dim3(16,64,1),blk,0,stream>>>(x, wv1, bv1, vb, NT,DIM,DIM, DIM,DIM,DIM, 1, 0,0,0,0,0,0, 1.f);

    // fused: probs (f32, d_out) + ctx (bf16, cb) in one pass pair
    full_attn_fused<<<dim3(SEQ/64, NH, BBS),blk,0,stream>>>(qb, kb, vb, attn_out, cb);

    // out projection 1 -> o1 f32
    gemm64<false,true,false,true,false,true><<<dim3(16,64,1),blk,0,stream>>>(cb, wo1, bo1, o1, NT,DIM,DIM, DIM,DIM,DIM, 1, 0,0,0,0,0,0, 1.f);

    // sum = LN(o1+x) + LN(o2+x) -> sumbf + sumf
    add_ln2_kernel<<<dim3(NT),blk,0,stream>>>(o1, o2, x, g1, be1, g2, be2, sumbf, sumf);

    // FFN (hbuf aliases qb..cb; ffo aliases o1 — both dead by now)
    gemm64<false,true,false,false,true,true><<<dim3(64,64,1),blk,0,stream>>>(sumbf, wc1, bc1, hbuf, NT,DFF_,DIM, DIM,DFF_,DFF_, 1, 0,0,0,0,0,0, 1.f);
    gemm64<false,true,false,true,false,true><<<dim3(16,64,1),blk,0,stream>>>(hbuf, wc2, bc2, ffo, NT,DIM,DFF_, DFF_,DIM,DIM, 1, 0,0,0,0,0,0, 1.f);

    // enc = LN(ffn_out + sum)
    final_ln_kernel<<<dim3(NT),blk,0,stream>>>(ffo, sumf, g3, be3, enc_out);
}